// Round 18
// baseline (94.157 us; speedup 1.0000x reference)
//
#include <hip/hip_runtime.h>
#include <math.h>

#define BB 4
#define CCH 256
#define NSP 2304   // 48*48
#define NHEAD 8
#define DH 32

typedef __bf16 bf16x4 __attribute__((ext_vector_type(4)));
typedef __bf16 bf16x8 __attribute__((ext_vector_type(8)));
typedef float f32x16 __attribute__((ext_vector_type(16)));
typedef unsigned u32x2 __attribute__((ext_vector_type(2)));
typedef unsigned u32x4 __attribute__((ext_vector_type(4)));

static __device__ __forceinline__ unsigned cvtpk(float lo, float hi) {
  unsigned r;
  asm("v_cvt_pk_bf16_f32 %0, %1, %2" : "=v"(r) : "v"(lo), "v"(hi));
  return r;
}

// pinned single-instruction exp2 / rcp
static __device__ __forceinline__ float fexp2(float x) {
  float r; asm("v_exp_f32 %0, %1" : "=v"(r) : "v"(x)); return r;
}
static __device__ __forceinline__ float frcp(float x) {
  float r; asm("v_rcp_f32 %0, %1" : "=v"(r) : "v"(x)); return r;
}

// ============ Pre-pass: Vx -> xt bf16 [b][n][ci]  +  conv_w -> wt bf16 =====
__global__ __launch_bounds__(256) void k_pre(const float* __restrict__ Vx,
    const float* __restrict__ cw, __bf16* __restrict__ xt, __bf16* __restrict__ wtb)
{
  __shared__ __bf16 Lt[64 * 40];
  const int tid = threadIdx.x;
  if (blockIdx.x < 1152) {
    int bid = blockIdx.x;
    const int nt = bid % 36; bid /= 36;
    const int cit = bid % 8; const int b = bid / 8;
    const int n0 = nt * 64, ci0 = cit * 32;
    {
      const int ci = tid >> 3, ns = (tid & 7) * 8;
      const float* src = Vx + ((size_t)(b * CCH + ci0 + ci)) * NSP + n0 + ns;
      float4 v0 = *(const float4*)src;
      float4 v1 = *(const float4*)(src + 4);
      Lt[(ns+0)*40 + ci] = (__bf16)v0.x;  Lt[(ns+1)*40 + ci] = (__bf16)v0.y;
      Lt[(ns+2)*40 + ci] = (__bf16)v0.z;  Lt[(ns+3)*40 + ci] = (__bf16)v0.w;
      Lt[(ns+4)*40 + ci] = (__bf16)v1.x;  Lt[(ns+5)*40 + ci] = (__bf16)v1.y;
      Lt[(ns+6)*40 + ci] = (__bf16)v1.z;  Lt[(ns+7)*40 + ci] = (__bf16)v1.w;
    }
    __syncthreads();
    {
      const int n = tid >> 2, cip = (tid & 3) * 8;
      bf16x8 r = *(bf16x8*)&Lt[n * 40 + cip];
      *(bf16x8*)&xt[((size_t)b * NSP + n0 + n) * CCH + ci0 + cip] = r;
    }
  } else {
    const int co = blockIdx.x - 1152, ci = tid;
    const float* rd = cw + ((size_t)co * CCH + ci) * 9;
#pragma unroll
    for (int p = 0; p < 9; ++p)
      wtb[((size_t)p * CCH + co) * CCH + ci] = (__bf16)rd[p];
  }
}

// ============ K1: conv3x3 implicit GEMM, 32co x 96n, 3 waves ===============
#define XLP 40

__global__ __launch_bounds__(192) void k_conv_mfma(const __bf16* __restrict__ xt,
    const __bf16* __restrict__ wt,
    const float* __restrict__ cb, const float* __restrict__ g,
    const float* __restrict__ be, const float* __restrict__ mu,
    const float* __restrict__ va, __bf16* __restrict__ xq)
{
  __shared__ __bf16 Xl[200 * XLP];
  __shared__ __bf16 Wl[9 * 32 * XLP];
  __shared__ float bn[32][2];
  const int bid0 = blockIdx.x;
  int bid = (bid0 & 7) * 96 + (bid0 >> 3);   // XCD swizzle (768 = 8*96)
  const int nt = bid % 24; bid /= 24;
  const int cot = bid % 8; const int b = bid / 8;
  const int n0 = nt * 96, co0 = cot * 32, row0 = nt * 2;
  const int tid = threadIdx.x;
  const int w = tid >> 6, l = tid & 63, h = l >> 5, q = l & 31;

  if (tid < 32) {
    const int co = co0 + tid;
    const float inv = g[co] * rsqrtf(va[co] + 1e-5f);
    bn[tid][0] = inv;
    bn[tid][1] = (cb[co] - mu[co]) * inv + be[co];
  }

  const int nabs = n0 + w * 32 + q;
  const int yab = nabs / 48, xab = nabs - yab * 48;
  const int sb = (yab - row0) * 50 + xab;

  const __bf16* xtb = xt + (size_t)b * NSP * CCH;

  f32x16 acc;
#pragma unroll
  for (int r = 0; r < 16; ++r) acc[r] = 0.f;

  for (int cc = 0; cc < 8; ++cc) {
    __syncthreads();
#pragma unroll
    for (int it = 0; it < 5; ++it) {
      const int v = it * 192 + tid;
      if (v < 800) {
        const int sp = v >> 2, cip = (v & 3) * 8;
        const int r = sp / 50, xp = sp - r * 50;
        const int gy = row0 - 1 + r, gx = xp - 1;
        bf16x8 val;
#pragma unroll
        for (int j = 0; j < 8; ++j) val[j] = (__bf16)0.f;
        if ((unsigned)gy < 48u && (unsigned)gx < 48u)
          val = *(const bf16x8*)&xtb[(size_t)(gy * 48 + gx) * CCH + cc * 32 + cip];
        *(bf16x8*)&Xl[sp * XLP + cip] = val;
      }
    }
    if (tid < 128) {
      const int co = tid >> 2, cip = (tid & 3) * 8;
      const __bf16* wsrc = wt + (size_t)(co0 + co) * CCH + cc * 32 + cip;
#pragma unroll
      for (int p = 0; p < 9; ++p)
        *(bf16x8*)&Wl[(p * 32 + co) * XLP + cip] =
            *(const bf16x8*)&wsrc[(size_t)p * CCH * CCH];
    }
    __syncthreads();
#pragma unroll
    for (int p = 0; p < 9; ++p) {
      const int dy = p / 3, dx = p - 3 * (p / 3);
#pragma unroll
      for (int ks = 0; ks < 2; ++ks) {
        bf16x8 a  = *(bf16x8*)&Wl[(p * 32 + q) * XLP + ks * 16 + 8 * h];
        bf16x8 bf = *(bf16x8*)&Xl[(sb + dy * 50 + dx) * XLP + ks * 16 + 8 * h];
        acc = __builtin_amdgcn_mfma_f32_32x32x16_bf16(a, bf, acc, 0, 0, 0);
      }
    }
  }

  __bf16* op = xq + ((size_t)b * NSP + nabs) * CCH + co0;
#pragma unroll
  for (int gg = 0; gg < 4; ++gg) {
    const int cl0 = 8 * gg + 4 * h;
    float v0 = fmaxf(fmaf(acc[4*gg+0], bn[cl0+0][0], bn[cl0+0][1]), 0.f);
    float v1 = fmaxf(fmaf(acc[4*gg+1], bn[cl0+1][0], bn[cl0+1][1]), 0.f);
    float v2 = fmaxf(fmaf(acc[4*gg+2], bn[cl0+2][0], bn[cl0+2][1]), 0.f);
    float v3 = fmaxf(fmaf(acc[4*gg+3], bn[cl0+3][0], bn[cl0+3][1]), 0.f);
    u32x2 pk; pk[0] = cvtpk(v0, v1); pk[1] = cvtpk(v2, v3);
    *(u32x2*)&op[cl0] = pk;
  }
}

// ============ K2: MFMA GEMM, QKV (64o x 128n tile, 4 waves) ================
__global__ __launch_bounds__(256) void k_gemm_mfma(const __bf16* __restrict__ X,
    const float* __restrict__ Wm, const float* __restrict__ bias,
    __bf16* __restrict__ Y)
{
  __shared__ __bf16 Xl[128 * XLP];
  __shared__ __bf16 Wl[64 * XLP];
  const int tid = threadIdx.x;
  int bid = blockIdx.x;
  const int nt = bid % 18; bid /= 18;
  const int ot = bid % 12; const int b = bid / 12;
  const int o0 = ot * 64, n0 = nt * 128;
  const int w = tid >> 6, l = tid & 63, h = l >> 5, q = l & 31;

  const int xrow = tid >> 1, xcip = (tid & 1) * 16;
  const int wrow = tid >> 2, wcip = (tid & 3) * 8;
  const __bf16* Xb = X + (size_t)b * NSP * CCH + (size_t)(n0 + xrow) * CCH;

  f32x16 acc0, acc1;
#pragma unroll
  for (int r = 0; r < 16; ++r) { acc0[r] = 0.f; acc1[r] = 0.f; }

  bf16x8 xa0, xa1; float4 wa0, wa1;
  xa0 = *(const bf16x8*)&Xb[xcip];
  xa1 = *(const bf16x8*)&Xb[xcip + 8];
  wa0 = *(const float4*)&Wm[(size_t)(o0 + wrow) * CCH + wcip];
  wa1 = *(const float4*)&Wm[(size_t)(o0 + wrow) * CCH + wcip + 4];

  for (int cc = 0; cc < 8; ++cc) {
    __syncthreads();
    *(bf16x8*)&Xl[xrow * XLP + xcip]     = xa0;
    *(bf16x8*)&Xl[xrow * XLP + xcip + 8] = xa1;
    {
      bf16x8 wv;
      wv[0]=(__bf16)wa0.x; wv[1]=(__bf16)wa0.y; wv[2]=(__bf16)wa0.z; wv[3]=(__bf16)wa0.w;
      wv[4]=(__bf16)wa1.x; wv[5]=(__bf16)wa1.y; wv[6]=(__bf16)wa1.z; wv[7]=(__bf16)wa1.w;
      *(bf16x8*)&Wl[wrow * XLP + wcip] = wv;
    }
    __syncthreads();
    if (cc < 7) {
      const int c1 = (cc + 1) * 32;
      xa0 = *(const bf16x8*)&Xb[c1 + xcip];
      xa1 = *(const bf16x8*)&Xb[c1 + xcip + 8];
      wa0 = *(const float4*)&Wm[(size_t)(o0 + wrow) * CCH + c1 + wcip];
      wa1 = *(const float4*)&Wm[(size_t)(o0 + wrow) * CCH + c1 + wcip + 4];
    }
#pragma unroll
    for (int ks = 0; ks < 2; ++ks) {
      bf16x8 a0 = *(bf16x8*)&Wl[q * XLP + ks * 16 + 8 * h];
      bf16x8 a1 = *(bf16x8*)&Wl[(32 + q) * XLP + ks * 16 + 8 * h];
      bf16x8 bfr = *(bf16x8*)&Xl[(w * 32 + q) * XLP + ks * 16 + 8 * h];
      acc0 = __builtin_amdgcn_mfma_f32_32x32x16_bf16(a0, bfr, acc0, 0, 0, 0);
      acc1 = __builtin_amdgcn_mfma_f32_32x32x16_bf16(a1, bfr, acc1, 0, 0, 0);
    }
  }

  const int n = n0 + w * 32 + q;
  const float QS = 1.4426950408889634f * 0.17677669529663687f;
#pragma unroll
  for (int j = 0; j < 2; ++j) {
    const int t = 2 * ot + j;
    const int head = t / 3, comp = t - 3 * (t / 3);
    const float sc = (comp == 0) ? QS : 1.0f;
    __bf16* yb = Y + (((size_t)(b * NHEAD + head) * 3 + comp) * NSP + n) * DH;
    const f32x16& A = j ? acc1 : acc0;
#pragma unroll
    for (int gg = 0; gg < 4; ++gg) {
      const int e0 = 8 * gg + 4 * h;
      const int ob = o0 + 32 * j + e0;
      u32x2 pk;
      pk[0] = cvtpk((A[4*gg+0] + bias[ob+0]) * sc, (A[4*gg+1] + bias[ob+1]) * sc);
      pk[1] = cvtpk((A[4*gg+2] + bias[ob+2]) * sc, (A[4*gg+3] + bias[ob+3]) * sc);
      *(u32x2*)&yb[e0] = pk;
    }
  }
}

// ============ K3: MFMA flash attention, K-split x3, 128-key steps ==========
// V staging: 4x global b64 (4 consecutive keys x 4 e) + in-register 4x4
// transpose + 4x ds_write_b64 along keys (bit-2<->3 key permutation is
// order-preserving on 4-aligned blocks). Replaces 16 scattered ds_write_b16.
#define KLS 40
#define VLS 136
#define NSPLIT 3
#define NST 6

__global__ __launch_bounds__(256, 4) void k_attn_mfma(const __bf16* __restrict__ qkvt,
    __bf16* __restrict__ parts, float* __restrict__ rss)
{
  __shared__ __bf16 K_lds[2][128 * KLS];   // 20480 B
  __shared__ __bf16 Vt_lds[2][32 * VLS];   // 17408 B
  const int tid = threadIdx.x;
  const int bid0 = blockIdx.x;
  // XCD swizzle over 1728 = 8 * 216
  const int bid = (bid0 & 7) * 216 + (bid0 >> 3);
  const int bh  = bid / 54;
  const int rem = bid % 54;
  const int qb  = rem / 3;
  const int ks  = rem % 3;
  const int w  = tid >> 6;
  const int l  = tid & 63;
  const int h  = l >> 5;
  const int q  = l & 31;

  const __bf16* qg = qkvt + ((size_t)bh * 3    ) * NSP * DH;
  const __bf16* kg = qkvt + ((size_t)bh * 3 + 1) * NSP * DH;
  const __bf16* vg = qkvt + ((size_t)bh * 3 + 2) * NSP * DH;

  const int nq = qb * 128 + w * 32 + q;
  bf16x8 qf0 = *(const bf16x8*)&qg[(size_t)nq * DH + 8 * h];
  bf16x8 qf1 = *(const bf16x8*)&qg[(size_t)nq * DH + 16 + 8 * h];

  f32x16 zf;
#pragma unroll
  for (int r = 0; r < 16; ++r) zf[r] = 0.f;

  f32x16 accO;
#pragma unroll
  for (int r = 0; r < 16; ++r) accO[r] = 0.f;
  float rs = 0.f;

  // K staging: 128 rows x 32 ci = 512 vec8; thread does rows krow, krow+64
  const int krow = tid >> 2, kcol = (tid & 3) * 8;
  // V staging: thread covers 4 consecutive keys (4-aligned) x 4 e's
  const int vkb = (tid & 31) * 4;          // key base 0,4,...,124
  const int veg = (tid >> 5) * 4;          // e base 0,4,...,28
  // bit 2<->3 swap of the 4-aligned base (order-preserving within block)
  const int vkp = (vkb & 115) | ((vkb & 4) << 1) | ((vkb & 8) >> 1);
  const int m0 = ks * (NST * 128);

  bf16x8 ka0 = *(const bf16x8*)&kg[(size_t)(m0 + krow) * DH + kcol];
  bf16x8 ka1 = *(const bf16x8*)&kg[(size_t)(m0 + krow + 64) * DH + kcol];
  bf16x4 va4[4];
#pragma unroll
  for (int j = 0; j < 4; ++j)
    va4[j] = *(const bf16x4*)&vg[(size_t)(m0 + vkb + j) * DH + veg];

  *(bf16x8*)&K_lds[0][krow * KLS + kcol] = ka0;
  *(bf16x8*)&K_lds[0][(krow + 64) * KLS + kcol] = ka1;
#pragma unroll
  for (int i = 0; i < 4; ++i) {
    bf16x4 vo = { va4[0][i], va4[1][i], va4[2][i], va4[3][i] };
    *(bf16x4*)&Vt_lds[0][(veg + i) * VLS + vkp] = vo;
  }
  ka0 = *(const bf16x8*)&kg[(size_t)(m0 + 128 + krow) * DH + kcol];
  ka1 = *(const bf16x8*)&kg[(size_t)(m0 + 128 + krow + 64) * DH + kcol];
#pragma unroll
  for (int j = 0; j < 4; ++j)
    va4[j] = *(const bf16x4*)&vg[(size_t)(m0 + 128 + vkb + j) * DH + veg];
  __syncthreads();

  for (int s = 0; s < NST; ++s) {
    const int cur = s & 1;
    if (s + 1 < NST) {
      *(bf16x8*)&K_lds[cur ^ 1][krow * KLS + kcol] = ka0;
      *(bf16x8*)&K_lds[cur ^ 1][(krow + 64) * KLS + kcol] = ka1;
#pragma unroll
      for (int i = 0; i < 4; ++i) {
        bf16x4 vo = { va4[0][i], va4[1][i], va4[2][i], va4[3][i] };
        *(bf16x4*)&Vt_lds[cur ^ 1][(veg + i) * VLS + vkp] = vo;
      }
      if (s + 2 < NST) {
        const int m2 = m0 + (s + 2) * 128;
        ka0 = *(const bf16x8*)&kg[(size_t)(m2 + krow) * DH + kcol];
        ka1 = *(const bf16x8*)&kg[(size_t)(m2 + krow + 64) * DH + kcol];
#pragma unroll
        for (int j = 0; j < 4; ++j)
          va4[j] = *(const bf16x4*)&vg[(size_t)(m2 + vkb + j) * DH + veg];
      }
    }
    __builtin_amdgcn_s_setprio(1);
#pragma unroll
    for (int kt = 0; kt < 4; ++kt) {
      bf16x8 kfr0 = *(bf16x8*)&K_lds[cur][(32*kt + q) * KLS + 8*h];
      bf16x8 kfr1 = *(bf16x8*)&K_lds[cur][(32*kt + q) * KLS + 16 + 8*h];
      f32x16 sv;
      sv = __builtin_amdgcn_mfma_f32_32x32x16_bf16(kfr0, qf0, zf, 0, 0, 0);
      sv = __builtin_amdgcn_mfma_f32_32x32x16_bf16(kfr1, qf1, sv, 0, 0, 0);
      float p[16];
#pragma unroll
      for (int r = 0; r < 16; ++r) { p[r] = fexp2(sv[r]); rs += p[r]; }
#pragma unroll
      for (int m = 0; m < 2; ++m) {
        u32x4 pw;
        pw[0] = cvtpk(p[8*m+0], p[8*m+1]);
        pw[1] = cvtpk(p[8*m+2], p[8*m+3]);
        pw[2] = cvtpk(p[8*m+4], p[8*m+5]);
        pw[3] = cvtpk(p[8*m+6], p[8*m+7]);
        bf16x8 pfr = __builtin_bit_cast(bf16x8, pw);
        const int MT = 2*kt + m;
        bf16x8 vfr = *(bf16x8*)&Vt_lds[cur][q * VLS + 16*MT + 8*h];
        accO = __builtin_amdgcn_mfma_f32_32x32x16_bf16(vfr, pfr, accO, 0, 0, 0);
      }
    }
    __builtin_amdgcn_s_setprio(0);
    __syncthreads();
  }

  // each lane holds half the keys' p-sum; partner (l^32) has the other half
  rs += __shfl_xor(rs, 32, 64);

  const int b = bh >> 3, head = bh & 7;
  __bf16* ob = parts + (size_t)ks * 2359296
             + ((size_t)b * NSP + nq) * CCH + head * DH;
#pragma unroll
  for (int gg = 0; gg < 4; ++gg) {
    const int e0 = 8 * gg + 4 * h;
    u32x2 pk;
    pk[0] = cvtpk(accO[4*gg+0], accO[4*gg+1]);
    pk[1] = cvtpk(accO[4*gg+2], accO[4*gg+3]);
    *(u32x2*)&ob[e0] = pk;
  }
  if (h == 0)
    rss[(size_t)ks * 73728 + (size_t)bh * NSP + nq] = rs;
}

// ============ K3b: combine 3 splits -> normalized x2 bf16 [b][n][256] ======
__global__ __launch_bounds__(256) void k_combine(const __bf16* __restrict__ parts,
    const float* __restrict__ rss, __bf16* __restrict__ x2)
{
  const int tid = threadIdx.x;
  const int row = blockIdx.x * 16 + (tid >> 4);      // b*NSP + n
  const int cseg = (tid & 15) * 16;
  const int b = row / NSP, n = row - b * NSP;
  const int head = cseg >> 5;
  const size_t ri = (size_t)(b * NHEAD + head) * NSP + n;
  const float rn = frcp(rss[ri] + rss[73728 + ri] + rss[2*73728 + ri]);

  const size_t base = (size_t)row * CCH + cseg;
  float s[16];
#pragma unroll
  for (int j = 0; j < 16; ++j) s[j] = 0.f;
#pragma unroll
  for (int ksp = 0; ksp < NSPLIT; ++ksp) {
    bf16x8 a0 = *(const bf16x8*)&parts[(size_t)ksp * 2359296 + base];
    bf16x8 a1 = *(const bf16x8*)&parts[(size_t)ksp * 2359296 + base + 8];
#pragma unroll
    for (int j = 0; j < 8; ++j) { s[j] += (float)a0[j]; s[8+j] += (float)a1[j]; }
  }
  u32x4 o0, o1;
#pragma unroll
  for (int j = 0; j < 4; ++j) {
    o0[j] = cvtpk(s[2*j] * rn,   s[2*j+1] * rn);
    o1[j] = cvtpk(s[8+2*j] * rn, s[8+2*j+1] * rn);
  }
  *(u32x4*)&x2[base] = o0;
  *(u32x4*)&x2[base + 8] = o1;
}

// ============ K4: proj GEMM (plain, 64o x 128n), fp32 out + bias ===========
__global__ __launch_bounds__(256) void k_proj_mfma(const __bf16* __restrict__ X,
    const float* __restrict__ Wm, const float* __restrict__ bias,
    float* __restrict__ Y)
{
  __shared__ __bf16 Xl[128 * XLP];
  __shared__ __bf16 Wl[64 * XLP];
  const int tid = threadIdx.x;
  int bid = blockIdx.x;
  const int nt = bid % 18; bid /= 18;
  const int ot = bid % 4; const int b = bid / 4;
  const int o0 = ot * 64, n0 = nt * 128;
  const int w = tid >> 6, l = tid & 63, h = l >> 5, q = l & 31;

  const int xrow = tid >> 1, xcip = (tid & 1) * 16;
  const int wrow = tid >> 2, wcip = (tid & 3) * 8;
  const __bf16* Xb = X + (size_t)b * NSP * CCH + (size_t)(n0 + xrow) * CCH;

  f32x16 acc0, acc1;
#pragma unroll
  for (int r = 0; r < 16; ++r) { acc0[r] = 0.f; acc1[r] = 0.f; }

  bf16x8 xa0, xa1; float4 wa0, wa1;
  xa0 = *(const bf16x8*)&Xb[xcip];
  xa1 = *(const bf16x8*)&Xb[xcip + 8];
  wa0 = *(const float4*)&Wm[(size_t)(o0 + wrow) * CCH + wcip];
  wa1 = *(const float4*)&Wm[(size_t)(o0 + wrow) * CCH + wcip + 4];

  for (int cc = 0; cc < 8; ++cc) {
    __syncthreads();
    *(bf16x8*)&Xl[xrow * XLP + xcip]     = xa0;
    *(bf16x8*)&Xl[xrow * XLP + xcip + 8] = xa1;
    {
      bf16x8 wv;
      wv[0]=(__bf16)wa0.x; wv[1]=(__bf16)wa0.y; wv[2]=(__bf16)wa0.z; wv[3]=(__bf16)wa0.w;
      wv[4]=(__bf16)wa1.x; wv[5]=(__bf16)wa1.y; wv[6]=(__bf16)wa1.z; wv[7]=(__bf16)wa1.w;
      *(bf16x8*)&Wl[wrow * XLP + wcip] = wv;
    }
    __syncthreads();
    if (cc < 7) {
      const int c1 = (cc + 1) * 32;
      xa0 = *(const bf16x8*)&Xb[c1 + xcip];
      xa1 = *(const bf16x8*)&Xb[c1 + xcip + 8];
      wa0 = *(const float4*)&Wm[(size_t)(o0 + wrow) * CCH + c1 + wcip];
      wa1 = *(const float4*)&Wm[(size_t)(o0 + wrow) * CCH + c1 + wcip + 4];
    }
#pragma unroll
    for (int ks = 0; ks < 2; ++ks) {
      bf16x8 a0 = *(bf16x8*)&Wl[q * XLP + ks * 16 + 8 * h];
      bf16x8 a1 = *(bf16x8*)&Wl[(32 + q) * XLP + ks * 16 + 8 * h];
      bf16x8 bfr = *(bf16x8*)&Xl[(w * 32 + q) * XLP + ks * 16 + 8 * h];
      acc0 = __builtin_amdgcn_mfma_f32_32x32x16_bf16(a0, bfr, acc0, 0, 0, 0);
      acc1 = __builtin_amdgcn_mfma_f32_32x32x16_bf16(a1, bfr, acc1, 0, 0, 0);
    }
  }

  const int n = n0 + w * 32 + q;
#pragma unroll
  for (int j = 0; j < 2; ++j) {
    const f32x16& A = j ? acc1 : acc0;
#pragma unroll
    for (int r = 0; r < 16; ++r) {
      const int e = (r & 3) + 8 * (r >> 2) + 4 * h;
      const int o = o0 + 32 * j + e;
      Y[((size_t)b * CCH + o) * NSP + n] = A[r] + bias[o];
    }
  }
}

// ---------------------------------------------------------------------------
extern "C" void kernel_launch(void* const* d_in, const int* in_sizes, int n_in,
                              void* d_out, int out_size, void* d_ws, size_t ws_size,
                              hipStream_t stream)
{
  const float* Vx = (const float*)d_in[0];
  const float* cw = (const float*)d_in[1];
  const float* cb = (const float*)d_in[2];
  const float* g  = (const float*)d_in[3];
  const float* be = (const float*)d_in[4];
  const float* mu = (const float*)d_in[5];
  const float* va = (const float*)d_in[6];
  const float* qw = (const float*)d_in[7];
  const float* qb = (const float*)d_in[8];
  const float* pw = (const float*)d_in[9];
  const float* pb = (const float*)d_in[10];
  float* out = (float*)d_out;

  // ws: xq 4.5M | qkv 13.5M | parts 3x4.5M | rss 3x288K | x2 4.5M
  __bf16* xq    = (__bf16*)d_ws;
  __bf16* qkvt  = (__bf16*)((char*)d_ws + 4718592);
  __bf16* parts = (__bf16*)((char*)d_ws + 18874368);
  float*  rss   = (float*) ((char*)d_ws + 33030144);
  __bf16* x2    = (__bf16*)((char*)d_ws + 34209792);

  // d_out doubles as scratch for conv operand pre-transposes
  __bf16* xt = (__bf16*)d_out;                       // 4.5 MiB
  __bf16* wt = (__bf16*)((char*)d_out + 4718592);    // 1.1 MiB

  k_pre<<<1408, 256, 0, stream>>>(Vx, cw, xt, wt);
  k_conv_mfma<<<768, 192, 0, stream>>>(xt, wt, cb, g, be, mu, va, xq);
  k_gemm_mfma<<<4*12*18, 256, 0, stream>>>(xq, qw, qb, qkvt);
  k_attn_mfma<<<1728, 256, 0, stream>>>(qkvt, parts, rss);
  k_combine<<<576, 256, 0, stream>>>(parts, rss, x2);
  k_proj_mfma<<<4*4*18, 256, 0, stream>>>(x2, pw, pb, out);
}

// Round 19
// 92.197 us; speedup vs baseline: 1.0213x; 1.0213x over previous
//
#include <hip/hip_runtime.h>
#include <math.h>

#define BB 4
#define CCH 256
#define NSP 2304   // 48*48
#define NHEAD 8
#define DH 32

typedef __bf16 bf16x8 __attribute__((ext_vector_type(8)));
typedef float f32x16 __attribute__((ext_vector_type(16)));
typedef unsigned u32x2 __attribute__((ext_vector_type(2)));
typedef unsigned u32x4 __attribute__((ext_vector_type(4)));

static __device__ __forceinline__ unsigned cvtpk(float lo, float hi) {
  unsigned r;
  asm("v_cvt_pk_bf16_f32 %0, %1, %2" : "=v"(r) : "v"(lo), "v"(hi));
  return r;
}

// pinned single-instruction exp2 / rcp
static __device__ __forceinline__ float fexp2(float x) {
  float r; asm("v_exp_f32 %0, %1" : "=v"(r) : "v"(x)); return r;
}
static __device__ __forceinline__ float frcp(float x) {
  float r; asm("v_rcp_f32 %0, %1" : "=v"(r) : "v"(x)); return r;
}

// ============ Pre-pass: Vx -> xt bf16 [b][n][ci]  +  conv_w -> wt bf16 =====
__global__ __launch_bounds__(256) void k_pre(const float* __restrict__ Vx,
    const float* __restrict__ cw, __bf16* __restrict__ xt, __bf16* __restrict__ wtb)
{
  __shared__ __bf16 Lt[64 * 40];
  const int tid = threadIdx.x;
  if (blockIdx.x < 1152) {
    int bid = blockIdx.x;
    const int nt = bid % 36; bid /= 36;
    const int cit = bid % 8; const int b = bid / 8;
    const int n0 = nt * 64, ci0 = cit * 32;
    {
      const int ci = tid >> 3, ns = (tid & 7) * 8;
      const float* src = Vx + ((size_t)(b * CCH + ci0 + ci)) * NSP + n0 + ns;
      float4 v0 = *(const float4*)src;
      float4 v1 = *(const float4*)(src + 4);
      Lt[(ns+0)*40 + ci] = (__bf16)v0.x;  Lt[(ns+1)*40 + ci] = (__bf16)v0.y;
      Lt[(ns+2)*40 + ci] = (__bf16)v0.z;  Lt[(ns+3)*40 + ci] = (__bf16)v0.w;
      Lt[(ns+4)*40 + ci] = (__bf16)v1.x;  Lt[(ns+5)*40 + ci] = (__bf16)v1.y;
      Lt[(ns+6)*40 + ci] = (__bf16)v1.z;  Lt[(ns+7)*40 + ci] = (__bf16)v1.w;
    }
    __syncthreads();
    {
      const int n = tid >> 2, cip = (tid & 3) * 8;
      bf16x8 r = *(bf16x8*)&Lt[n * 40 + cip];
      *(bf16x8*)&xt[((size_t)b * NSP + n0 + n) * CCH + ci0 + cip] = r;
    }
  } else {
    const int co = blockIdx.x - 1152, ci = tid;
    const float* rd = cw + ((size_t)co * CCH + ci) * 9;
#pragma unroll
    for (int p = 0; p < 9; ++p)
      wtb[((size_t)p * CCH + co) * CCH + ci] = (__bf16)rd[p];
  }
}

// ============ K1: conv3x3 implicit GEMM, 32co x 96n, 3 waves ===============
#define XLP 40

__global__ __launch_bounds__(192) void k_conv_mfma(const __bf16* __restrict__ xt,
    const __bf16* __restrict__ wt,
    const float* __restrict__ cb, const float* __restrict__ g,
    const float* __restrict__ be, const float* __restrict__ mu,
    const float* __restrict__ va, __bf16* __restrict__ xq)
{
  __shared__ __bf16 Xl[200 * XLP];
  __shared__ __bf16 Wl[9 * 32 * XLP];
  __shared__ float bn[32][2];
  const int bid0 = blockIdx.x;
  int bid = (bid0 & 7) * 96 + (bid0 >> 3);   // XCD swizzle (768 = 8*96)
  const int nt = bid % 24; bid /= 24;
  const int cot = bid % 8; const int b = bid / 8;
  const int n0 = nt * 96, co0 = cot * 32, row0 = nt * 2;
  const int tid = threadIdx.x;
  const int w = tid >> 6, l = tid & 63, h = l >> 5, q = l & 31;

  if (tid < 32) {
    const int co = co0 + tid;
    const float inv = g[co] * rsqrtf(va[co] + 1e-5f);
    bn[tid][0] = inv;
    bn[tid][1] = (cb[co] - mu[co]) * inv + be[co];
  }

  const int nabs = n0 + w * 32 + q;
  const int yab = nabs / 48, xab = nabs - yab * 48;
  const int sb = (yab - row0) * 50 + xab;

  const __bf16* xtb = xt + (size_t)b * NSP * CCH;

  f32x16 acc;
#pragma unroll
  for (int r = 0; r < 16; ++r) acc[r] = 0.f;

  for (int cc = 0; cc < 8; ++cc) {
    __syncthreads();
#pragma unroll
    for (int it = 0; it < 5; ++it) {
      const int v = it * 192 + tid;
      if (v < 800) {
        const int sp = v >> 2, cip = (v & 3) * 8;
        const int r = sp / 50, xp = sp - r * 50;
        const int gy = row0 - 1 + r, gx = xp - 1;
        bf16x8 val;
#pragma unroll
        for (int j = 0; j < 8; ++j) val[j] = (__bf16)0.f;
        if ((unsigned)gy < 48u && (unsigned)gx < 48u)
          val = *(const bf16x8*)&xtb[(size_t)(gy * 48 + gx) * CCH + cc * 32 + cip];
        *(bf16x8*)&Xl[sp * XLP + cip] = val;
      }
    }
    if (tid < 128) {
      const int co = tid >> 2, cip = (tid & 3) * 8;
      const __bf16* wsrc = wt + (size_t)(co0 + co) * CCH + cc * 32 + cip;
#pragma unroll
      for (int p = 0; p < 9; ++p)
        *(bf16x8*)&Wl[(p * 32 + co) * XLP + cip] =
            *(const bf16x8*)&wsrc[(size_t)p * CCH * CCH];
    }
    __syncthreads();
#pragma unroll
    for (int p = 0; p < 9; ++p) {
      const int dy = p / 3, dx = p - 3 * (p / 3);
#pragma unroll
      for (int ks = 0; ks < 2; ++ks) {
        bf16x8 a  = *(bf16x8*)&Wl[(p * 32 + q) * XLP + ks * 16 + 8 * h];
        bf16x8 bf = *(bf16x8*)&Xl[(sb + dy * 50 + dx) * XLP + ks * 16 + 8 * h];
        acc = __builtin_amdgcn_mfma_f32_32x32x16_bf16(a, bf, acc, 0, 0, 0);
      }
    }
  }

  __bf16* op = xq + ((size_t)b * NSP + nabs) * CCH + co0;
#pragma unroll
  for (int gg = 0; gg < 4; ++gg) {
    const int cl0 = 8 * gg + 4 * h;
    float v0 = fmaxf(fmaf(acc[4*gg+0], bn[cl0+0][0], bn[cl0+0][1]), 0.f);
    float v1 = fmaxf(fmaf(acc[4*gg+1], bn[cl0+1][0], bn[cl0+1][1]), 0.f);
    float v2 = fmaxf(fmaf(acc[4*gg+2], bn[cl0+2][0], bn[cl0+2][1]), 0.f);
    float v3 = fmaxf(fmaf(acc[4*gg+3], bn[cl0+3][0], bn[cl0+3][1]), 0.f);
    u32x2 pk; pk[0] = cvtpk(v0, v1); pk[1] = cvtpk(v2, v3);
    *(u32x2*)&op[cl0] = pk;
  }
}

// ============ K2: MFMA GEMM, QKV (64o x 128n tile, 4 waves) ================
__global__ __launch_bounds__(256) void k_gemm_mfma(const __bf16* __restrict__ X,
    const float* __restrict__ Wm, const float* __restrict__ bias,
    __bf16* __restrict__ Y)
{
  __shared__ __bf16 Xl[128 * XLP];
  __shared__ __bf16 Wl[64 * XLP];
  const int tid = threadIdx.x;
  int bid = blockIdx.x;
  const int nt = bid % 18; bid /= 18;
  const int ot = bid % 12; const int b = bid / 12;
  const int o0 = ot * 64, n0 = nt * 128;
  const int w = tid >> 6, l = tid & 63, h = l >> 5, q = l & 31;

  const int xrow = tid >> 1, xcip = (tid & 1) * 16;
  const int wrow = tid >> 2, wcip = (tid & 3) * 8;
  const __bf16* Xb = X + (size_t)b * NSP * CCH + (size_t)(n0 + xrow) * CCH;

  f32x16 acc0, acc1;
#pragma unroll
  for (int r = 0; r < 16; ++r) { acc0[r] = 0.f; acc1[r] = 0.f; }

  bf16x8 xa0, xa1; float4 wa0, wa1;
  xa0 = *(const bf16x8*)&Xb[xcip];
  xa1 = *(const bf16x8*)&Xb[xcip + 8];
  wa0 = *(const float4*)&Wm[(size_t)(o0 + wrow) * CCH + wcip];
  wa1 = *(const float4*)&Wm[(size_t)(o0 + wrow) * CCH + wcip + 4];

  for (int cc = 0; cc < 8; ++cc) {
    __syncthreads();
    *(bf16x8*)&Xl[xrow * XLP + xcip]     = xa0;
    *(bf16x8*)&Xl[xrow * XLP + xcip + 8] = xa1;
    {
      bf16x8 wv;
      wv[0]=(__bf16)wa0.x; wv[1]=(__bf16)wa0.y; wv[2]=(__bf16)wa0.z; wv[3]=(__bf16)wa0.w;
      wv[4]=(__bf16)wa1.x; wv[5]=(__bf16)wa1.y; wv[6]=(__bf16)wa1.z; wv[7]=(__bf16)wa1.w;
      *(bf16x8*)&Wl[wrow * XLP + wcip] = wv;
    }
    __syncthreads();
    if (cc < 7) {
      const int c1 = (cc + 1) * 32;
      xa0 = *(const bf16x8*)&Xb[c1 + xcip];
      xa1 = *(const bf16x8*)&Xb[c1 + xcip + 8];
      wa0 = *(const float4*)&Wm[(size_t)(o0 + wrow) * CCH + c1 + wcip];
      wa1 = *(const float4*)&Wm[(size_t)(o0 + wrow) * CCH + c1 + wcip + 4];
    }
#pragma unroll
    for (int ks = 0; ks < 2; ++ks) {
      bf16x8 a0 = *(bf16x8*)&Wl[q * XLP + ks * 16 + 8 * h];
      bf16x8 a1 = *(bf16x8*)&Wl[(32 + q) * XLP + ks * 16 + 8 * h];
      bf16x8 bfr = *(bf16x8*)&Xl[(w * 32 + q) * XLP + ks * 16 + 8 * h];
      acc0 = __builtin_amdgcn_mfma_f32_32x32x16_bf16(a0, bfr, acc0, 0, 0, 0);
      acc1 = __builtin_amdgcn_mfma_f32_32x32x16_bf16(a1, bfr, acc1, 0, 0, 0);
    }
  }

  const int n = n0 + w * 32 + q;
  const float QS = 1.4426950408889634f * 0.17677669529663687f;
#pragma unroll
  for (int j = 0; j < 2; ++j) {
    const int t = 2 * ot + j;
    const int head = t / 3, comp = t - 3 * (t / 3);
    const float sc = (comp == 0) ? QS : 1.0f;
    __bf16* yb = Y + (((size_t)(b * NHEAD + head) * 3 + comp) * NSP + n) * DH;
    const f32x16& A = j ? acc1 : acc0;
#pragma unroll
    for (int gg = 0; gg < 4; ++gg) {
      const int e0 = 8 * gg + 4 * h;
      const int ob = o0 + 32 * j + e0;
      u32x2 pk;
      pk[0] = cvtpk((A[4*gg+0] + bias[ob+0]) * sc, (A[4*gg+1] + bias[ob+1]) * sc);
      pk[1] = cvtpk((A[4*gg+2] + bias[ob+2]) * sc, (A[4*gg+3] + bias[ob+3]) * sc);
      *(u32x2*)&yb[e0] = pk;
    }
  }
}

// ============ K3: MFMA flash attention, K-split x3, 128-key steps ==========
// 6 steps of 128 keys per block. Single accumulator + launch_bounds(256,4);
// V staged bit-2<->3-swapped (C-layout/B-layout align, no permlane).
#define KLS 40
#define VLS 136
#define NSPLIT 3
#define NST 6

__global__ __launch_bounds__(256, 4) void k_attn_mfma(const __bf16* __restrict__ qkvt,
    __bf16* __restrict__ parts, float* __restrict__ rss)
{
  __shared__ __bf16 K_lds[2][128 * KLS];   // 20480 B
  __shared__ __bf16 Vt_lds[2][32 * VLS];   // 17408 B
  const int tid = threadIdx.x;
  const int bid0 = blockIdx.x;
  // XCD swizzle over 1728 = 8 * 216
  const int bid = (bid0 & 7) * 216 + (bid0 >> 3);
  const int bh  = bid / 54;
  const int rem = bid % 54;
  const int qb  = rem / 3;
  const int ks  = rem % 3;
  const int w  = tid >> 6;
  const int l  = tid & 63;
  const int h  = l >> 5;
  const int q  = l & 31;

  const __bf16* qg = qkvt + ((size_t)bh * 3    ) * NSP * DH;
  const __bf16* kg = qkvt + ((size_t)bh * 3 + 1) * NSP * DH;
  const __bf16* vg = qkvt + ((size_t)bh * 3 + 2) * NSP * DH;

  const int nq = qb * 128 + w * 32 + q;
  bf16x8 qf0 = *(const bf16x8*)&qg[(size_t)nq * DH + 8 * h];
  bf16x8 qf1 = *(const bf16x8*)&qg[(size_t)nq * DH + 16 + 8 * h];

  f32x16 zf;
#pragma unroll
  for (int r = 0; r < 16; ++r) zf[r] = 0.f;

  f32x16 accO;
#pragma unroll
  for (int r = 0; r < 16; ++r) accO[r] = 0.f;
  float rs = 0.f;

  // K staging: 128 rows x 32 ci = 512 vec8; thread does rows krow, krow+64
  const int krow = tid >> 2, kcol = (tid & 3) * 8;
  // V staging: 128 keys x 32 e; thread does key (tid&127), 16 e's
  const int vrow = tid & 127, vcol = (tid >> 7) * 16;
  // permuted V key: swap bits 2<->3 within each 32-key block
  const int vprm = (vrow & 115) | ((vrow & 4) << 1) | ((vrow & 8) >> 1);
  const int m0 = ks * (NST * 128);

  bf16x8 ka0 = *(const bf16x8*)&kg[(size_t)(m0 + krow) * DH + kcol];
  bf16x8 ka1 = *(const bf16x8*)&kg[(size_t)(m0 + krow + 64) * DH + kcol];
  bf16x8 va0 = *(const bf16x8*)&vg[(size_t)(m0 + vrow) * DH + vcol];
  bf16x8 va1 = *(const bf16x8*)&vg[(size_t)(m0 + vrow) * DH + vcol + 8];
  *(bf16x8*)&K_lds[0][krow * KLS + kcol] = ka0;
  *(bf16x8*)&K_lds[0][(krow + 64) * KLS + kcol] = ka1;
#pragma unroll
  for (int j = 0; j < 8; ++j) {
    Vt_lds[0][(vcol + j) * VLS + vprm]     = va0[j];
    Vt_lds[0][(vcol + 8 + j) * VLS + vprm] = va1[j];
  }
  ka0 = *(const bf16x8*)&kg[(size_t)(m0 + 128 + krow) * DH + kcol];
  ka1 = *(const bf16x8*)&kg[(size_t)(m0 + 128 + krow + 64) * DH + kcol];
  va0 = *(const bf16x8*)&vg[(size_t)(m0 + 128 + vrow) * DH + vcol];
  va1 = *(const bf16x8*)&vg[(size_t)(m0 + 128 + vrow) * DH + vcol + 8];
  __syncthreads();

  for (int s = 0; s < NST; ++s) {
    const int cur = s & 1;
    if (s + 1 < NST) {
      *(bf16x8*)&K_lds[cur ^ 1][krow * KLS + kcol] = ka0;
      *(bf16x8*)&K_lds[cur ^ 1][(krow + 64) * KLS + kcol] = ka1;
#pragma unroll
      for (int j = 0; j < 8; ++j) {
        Vt_lds[cur ^ 1][(vcol + j) * VLS + vprm]     = va0[j];
        Vt_lds[cur ^ 1][(vcol + 8 + j) * VLS + vprm] = va1[j];
      }
      if (s + 2 < NST) {
        const int m2 = m0 + (s + 2) * 128;
        ka0 = *(const bf16x8*)&kg[(size_t)(m2 + krow) * DH + kcol];
        ka1 = *(const bf16x8*)&kg[(size_t)(m2 + krow + 64) * DH + kcol];
        va0 = *(const bf16x8*)&vg[(size_t)(m2 + vrow) * DH + vcol];
        va1 = *(const bf16x8*)&vg[(size_t)(m2 + vrow) * DH + vcol + 8];
      }
    }
    __builtin_amdgcn_s_setprio(1);
#pragma unroll
    for (int kt = 0; kt < 4; ++kt) {
      bf16x8 kfr0 = *(bf16x8*)&K_lds[cur][(32*kt + q) * KLS + 8*h];
      bf16x8 kfr1 = *(bf16x8*)&K_lds[cur][(32*kt + q) * KLS + 16 + 8*h];
      f32x16 sv;
      sv = __builtin_amdgcn_mfma_f32_32x32x16_bf16(kfr0, qf0, zf, 0, 0, 0);
      sv = __builtin_amdgcn_mfma_f32_32x32x16_bf16(kfr1, qf1, sv, 0, 0, 0);
      float p[16];
#pragma unroll
      for (int r = 0; r < 16; ++r) { p[r] = fexp2(sv[r]); rs += p[r]; }
#pragma unroll
      for (int m = 0; m < 2; ++m) {
        u32x4 pw;
        pw[0] = cvtpk(p[8*m+0], p[8*m+1]);
        pw[1] = cvtpk(p[8*m+2], p[8*m+3]);
        pw[2] = cvtpk(p[8*m+4], p[8*m+5]);
        pw[3] = cvtpk(p[8*m+6], p[8*m+7]);
        bf16x8 pfr = __builtin_bit_cast(bf16x8, pw);
        const int MT = 2*kt + m;
        bf16x8 vfr = *(bf16x8*)&Vt_lds[cur][q * VLS + 16*MT + 8*h];
        accO = __builtin_amdgcn_mfma_f32_32x32x16_bf16(vfr, pfr, accO, 0, 0, 0);
      }
    }
    __builtin_amdgcn_s_setprio(0);
    __syncthreads();
  }

  // each lane holds half the keys' p-sum; partner (l^32) has the other half
  rs += __shfl_xor(rs, 32, 64);

  const int b = bh >> 3, head = bh & 7;
  __bf16* ob = parts + (size_t)ks * 2359296
             + ((size_t)b * NSP + nq) * CCH + head * DH;
#pragma unroll
  for (int gg = 0; gg < 4; ++gg) {
    const int e0 = 8 * gg + 4 * h;
    u32x2 pk;
    pk[0] = cvtpk(accO[4*gg+0], accO[4*gg+1]);
    pk[1] = cvtpk(accO[4*gg+2], accO[4*gg+3]);
    *(u32x2*)&ob[e0] = pk;
  }
  if (h == 0)
    rss[(size_t)ks * 73728 + (size_t)bh * NSP + nq] = rs;
}

// ============ K3b: combine 3 splits -> normalized x2 bf16 [b][n][256] ======
__global__ __launch_bounds__(256) void k_combine(const __bf16* __restrict__ parts,
    const float* __restrict__ rss, __bf16* __restrict__ x2)
{
  const int tid = threadIdx.x;
  const int row = blockIdx.x * 16 + (tid >> 4);      // b*NSP + n
  const int cseg = (tid & 15) * 16;
  const int b = row / NSP, n = row - b * NSP;
  const int head = cseg >> 5;
  const size_t ri = (size_t)(b * NHEAD + head) * NSP + n;
  const float rn = frcp(rss[ri] + rss[73728 + ri] + rss[2*73728 + ri]);

  const size_t base = (size_t)row * CCH + cseg;
  float s[16];
#pragma unroll
  for (int j = 0; j < 16; ++j) s[j] = 0.f;
#pragma unroll
  for (int ksp = 0; ksp < NSPLIT; ++ksp) {
    bf16x8 a0 = *(const bf16x8*)&parts[(size_t)ksp * 2359296 + base];
    bf16x8 a1 = *(const bf16x8*)&parts[(size_t)ksp * 2359296 + base + 8];
#pragma unroll
    for (int j = 0; j < 8; ++j) { s[j] += (float)a0[j]; s[8+j] += (float)a1[j]; }
  }
  u32x4 o0, o1;
#pragma unroll
  for (int j = 0; j < 4; ++j) {
    o0[j] = cvtpk(s[2*j] * rn,   s[2*j+1] * rn);
    o1[j] = cvtpk(s[8+2*j] * rn, s[8+2*j+1] * rn);
  }
  *(u32x4*)&x2[base] = o0;
  *(u32x4*)&x2[base + 8] = o1;
}

// ============ K4: proj GEMM (plain, 64o x 128n), fp32 out + bias ===========
__global__ __launch_bounds__(256) void k_proj_mfma(const __bf16* __restrict__ X,
    const float* __restrict__ Wm, const float* __restrict__ bias,
    float* __restrict__ Y)
{
  __shared__ __bf16 Xl[128 * XLP];
  __shared__ __bf16 Wl[64 * XLP];
  const int tid = threadIdx.x;
  int bid = blockIdx.x;
  const int nt = bid % 18; bid /= 18;
  const int ot = bid % 4; const int b = bid / 4;
  const int o0 = ot * 64, n0 = nt * 128;
  const int w = tid >> 6, l = tid & 63, h = l >> 5, q = l & 31;

  const int xrow = tid >> 1, xcip = (tid & 1) * 16;
  const int wrow = tid >> 2, wcip = (tid & 3) * 8;
  const __bf16* Xb = X + (size_t)b * NSP * CCH + (size_t)(n0 + xrow) * CCH;

  f32x16 acc0, acc1;
#pragma unroll
  for (int r = 0; r < 16; ++r) { acc0[r] = 0.f; acc1[r] = 0.f; }

  bf16x8 xa0, xa1; float4 wa0, wa1;
  xa0 = *(const bf16x8*)&Xb[xcip];
  xa1 = *(const bf16x8*)&Xb[xcip + 8];
  wa0 = *(const float4*)&Wm[(size_t)(o0 + wrow) * CCH + wcip];
  wa1 = *(const float4*)&Wm[(size_t)(o0 + wrow) * CCH + wcip + 4];

  for (int cc = 0; cc < 8; ++cc) {
    __syncthreads();
    *(bf16x8*)&Xl[xrow * XLP + xcip]     = xa0;
    *(bf16x8*)&Xl[xrow * XLP + xcip + 8] = xa1;
    {
      bf16x8 wv;
      wv[0]=(__bf16)wa0.x; wv[1]=(__bf16)wa0.y; wv[2]=(__bf16)wa0.z; wv[3]=(__bf16)wa0.w;
      wv[4]=(__bf16)wa1.x; wv[5]=(__bf16)wa1.y; wv[6]=(__bf16)wa1.z; wv[7]=(__bf16)wa1.w;
      *(bf16x8*)&Wl[wrow * XLP + wcip] = wv;
    }
    __syncthreads();
    if (cc < 7) {
      const int c1 = (cc + 1) * 32;
      xa0 = *(const bf16x8*)&Xb[c1 + xcip];
      xa1 = *(const bf16x8*)&Xb[c1 + xcip + 8];
      wa0 = *(const float4*)&Wm[(size_t)(o0 + wrow) * CCH + c1 + wcip];
      wa1 = *(const float4*)&Wm[(size_t)(o0 + wrow) * CCH + c1 + wcip + 4];
    }
#pragma unroll
    for (int ks = 0; ks < 2; ++ks) {
      bf16x8 a0 = *(bf16x8*)&Wl[q * XLP + ks * 16 + 8 * h];
      bf16x8 a1 = *(bf16x8*)&Wl[(32 + q) * XLP + ks * 16 + 8 * h];
      bf16x8 bfr = *(bf16x8*)&Xl[(w * 32 + q) * XLP + ks * 16 + 8 * h];
      acc0 = __builtin_amdgcn_mfma_f32_32x32x16_bf16(a0, bfr, acc0, 0, 0, 0);
      acc1 = __builtin_amdgcn_mfma_f32_32x32x16_bf16(a1, bfr, acc1, 0, 0, 0);
    }
  }

  const int n = n0 + w * 32 + q;
#pragma unroll
  for (int j = 0; j < 2; ++j) {
    const f32x16& A = j ? acc1 : acc0;
#pragma unroll
    for (int r = 0; r < 16; ++r) {
      const int e = (r & 3) + 8 * (r >> 2) + 4 * h;
      const int o = o0 + 32 * j + e;
      Y[((size_t)b * CCH + o) * NSP + n] = A[r] + bias[o];
    }
  }
}

// ---------------------------------------------------------------------------
extern "C" void kernel_launch(void* const* d_in, const int* in_sizes, int n_in,
                              void* d_out, int out_size, void* d_ws, size_t ws_size,
                              hipStream_t stream)
{
  const float* Vx = (const float*)d_in[0];
  const float* cw = (const float*)d_in[1];
  const float* cb = (const float*)d_in[2];
  const float* g  = (const float*)d_in[3];
  const float* be = (const float*)d_in[4];
  const float* mu = (const float*)d_in[5];
  const float* va = (const float*)d_in[6];
  const float* qw = (const float*)d_in[7];
  const float* qb = (const float*)d_in[8];
  const float* pw = (const float*)d_in[9];
  const float* pb = (const float*)d_in[10];
  float* out = (float*)d_out;

  // ws: xq 4.5M | qkv 13.5M | parts 3x4.5M | rss 3x288K | x2 4.5M
  __bf16* xq    = (__bf16*)d_ws;
  __bf16* qkvt  = (__bf16*)((char*)d_ws + 4718592);
  __bf16* parts = (__bf16*)((char*)d_ws + 18874368);
  float*  rss   = (float*) ((char*)d_ws + 33030144);
  __bf16* x2    = (__bf16*)((char*)d_ws + 34209792);

  // d_out doubles as scratch for conv operand pre-transposes
  __bf16* xt = (__bf16*)d_out;                       // 4.5 MiB
  __bf16* wt = (__bf16*)((char*)d_out + 4718592);    // 1.1 MiB

  k_pre<<<1408, 256, 0, stream>>>(Vx, cw, xt, wt);
  k_conv_mfma<<<768, 192, 0, stream>>>(xt, wt, cb, g, be, mu, va, xq);
  k_gemm_mfma<<<4*12*18, 256, 0, stream>>>(xq, qw, qb, qkvt);
  k_attn_mfma<<<1728, 256, 0, stream>>>(qkvt, parts, rss);
  k_combine<<<576, 256, 0, stream>>>(parts, rss, x2);
  k_proj_mfma<<<4*4*18, 256, 0, stream>>>(x2, pw, pb, out);
}